// Round 1
// baseline (1360.049 us; speedup 1.0000x reference)
//
#include <hip/hip_runtime.h>
#include <math.h>

#define BB 32
#define WINL 512
#define CHN 64
#define FF 257
#define DM 128
#define DI 256
#define DSTATE 16
#define M1 (BB*FF)        /* 8224  rows per variant */
#define M3 (3*M1)         /* 24672 rows total       */

/* ---- workspace layout (float offsets) ---- */
static const long TW_OFF   = 0;                                /* cos[512], sin[512] */
static const long ANEG_OFF = 1024;                             /* A = -exp(A_log), 256*16 */
static const long SIG_OFF  = 5120;                             /* coarse, fine signals: 2*B*WIN*CH */
static const long SFRE_OFF = SIG_OFF  + 2L*BB*WINL*CHN;        /* 3*M1*CHN */
static const long SFIM_OFF = SFRE_OFF + 3L*M1*CHN;
static const long EMB_OFF  = SFIM_OFF + 3L*M1*CHN;             /* 3*M1*DM; later reused as XDBL (3*M1*40) */
static const long XZ_OFF   = EMB_OFF  + 3L*M1*DM;              /* 3*M1*512 */
static const long XC_OFF   = XZ_OFF   + 3L*M1*2*DI;            /* 3*M1*256 */
static const long DT_OFF   = XC_OFF   + 3L*M1*DI;              /* 3*M1*256; scan overwrites in-place with y */
static const long ENC_OFF  = DT_OFF   + 3L*M1*DI;              /* 3*M1*128 */
static const long REAL_OFF = ENC_OFF  + 3L*M1*DM;              /* M1*64 */
static const long IMAG_OFF = REAL_OFF + 1L*M1*CHN;
static const long NRM_OFF  = IMAG_OFF + 1L*M1*CHN;             /* 3*32 norms */
static const long SIM_OFF  = NRM_OFF  + 128;                   /* 2*32*32 */
static const long RED_OFF  = SIM_OFF  + 2048;                  /* 512 partials */

/* ---- init: twiddles + A = -exp(A_log) ---- */
__global__ void k_init(float* ws, const float* __restrict__ A_log) {
    int i = blockIdx.x * 256 + threadIdx.x;
    if (i < 512) {
        double ang = (double)i * (3.14159265358979323846 / 256.0);
        ws[TW_OFF + i]       = (float)cos(ang);
        ws[TW_OFF + 512 + i] = (float)sin(ang);
    }
    int j = i - 512;
    if (j >= 0 && j < DI * DSTATE) ws[ANEG_OFF + j] = -expf(A_log[j]);
}

/* ---- augment: coarse = x*(u_mask>0.3), fine = x + 0.3*jitter ---- */
__global__ void k_aug(const float* __restrict__ x, const float* __restrict__ jit,
                      const float* __restrict__ um, float* ws) {
    long i = (long)blockIdx.x * 256 + threadIdx.x;
    if (i >= (long)BB * WINL * CHN) return;
    float xv = x[i];
    float m  = (um[i >> 6] > 0.3f) ? 1.f : 0.f;
    ws[SIG_OFF + i] = xv * m;
    ws[SIG_OFF + (long)BB * WINL * CHN + i] = fmaf(0.3f, jit[i], xv);
}

/* ---- direct rDFT, table-driven: block=(64 ch, 4 f) ---- */
__global__ __launch_bounds__(256) void k_dft(const float* __restrict__ x, float* ws) {
    __shared__ float twc[512], tws[512];
    int tid = threadIdx.y * 64 + threadIdx.x;
    for (int q = tid; q < 512; q += 256) { twc[q] = ws[TW_OFF + q]; tws[q] = ws[TW_OFF + 512 + q]; }
    __syncthreads();
    int ch = threadIdx.x;
    int f  = blockIdx.x * 4 + threadIdx.y;
    int b  = blockIdx.y, v = blockIdx.z;
    if (f >= FF) return;
    const float* src = (v == 0) ? x : (ws + SIG_OFF + (long)(v - 1) * BB * WINL * CHN);
    const float* col = src + (long)b * WINL * CHN + ch;
    float are = 0.f, aim = 0.f;
    int idx = 0;
    #pragma unroll 4
    for (int t = 0; t < WINL; ++t) {
        float s = col[(long)t * CHN];
        are = fmaf(s,  twc[idx], are);
        aim = fmaf(s, -tws[idx], aim);
        idx = (idx + f) & 511;
    }
    long m = (long)v * M1 + (long)b * FF + f;
    ws[SFRE_OFF + m * CHN + ch] = are;
    ws[SFIM_OFF + m * CHN + ch] = aim;
}

/* ---- generic naive GEMM: C[m,n] = sum_k A[m,k]B[k,n] (+bias)(softplus)
   A split into A1 (K1 cols) and optional A2 (K2 cols).  block=(64,4). ---- */
__global__ __launch_bounds__(256) void k_gemm(
    const float* __restrict__ A1, int lda1, int K1,
    const float* __restrict__ A2, int lda2, int K2,
    const float* __restrict__ Bm, int ldb,
    const float* __restrict__ bias,
    float* __restrict__ C, int ldc, int M, int N, int mode)
{
    int n = blockIdx.x * 64 + threadIdx.x;
    int m = blockIdx.y * 4 + threadIdx.y;
    if (m >= M || n >= N) return;
    const float* a = A1 + (long)m * lda1;
    float acc = 0.f;
    #pragma unroll 4
    for (int k = 0; k < K1; ++k) acc = fmaf(a[k], Bm[(long)k * ldb + n], acc);
    if (A2) {
        const float* a2 = A2 + (long)m * lda2;
        const float* B2 = Bm + (long)K1 * ldb;
        #pragma unroll 4
        for (int k = 0; k < K2; ++k) acc = fmaf(a2[k], B2[(long)k * ldb + n], acc);
    }
    if (mode >= 1) acc += bias[n];
    if (mode == 2) acc = (acc > 20.f) ? acc : log1pf(expf(acc));  /* softplus */
    C[(long)m * ldc + n] = acc;
}

/* ---- depthwise causal conv (K=4) + SiLU: block=256 d, grid=(257,32,3) ---- */
__global__ __launch_bounds__(256) void k_conv(const float* __restrict__ cw,
                                              const float* __restrict__ cb, float* ws) {
    int d = threadIdx.x;
    int t = blockIdx.x, b = blockIdx.y, v = blockIdx.z;
    long m0 = (long)v * M1 + (long)b * FF;
    const float* xz = ws + XZ_OFF;
    float acc = cb[d];
    #pragma unroll
    for (int k = 0; k < 4; ++k) {
        int tt = t - 3 + k;
        if (tt >= 0) acc = fmaf(cw[d * 4 + k], xz[(m0 + tt) * (2 * DI) + d], acc);
    }
    float sg = 1.f / (1.f + expf(-acc));
    ws[XC_OFF + (m0 + t) * DI + d] = acc * sg;
}

/* ---- selective scan, fused dA/dBu + epilogue (y+xc*D)*silu(z), in-place over dt ---- */
__global__ __launch_bounds__(256) void k_scan(const float* __restrict__ Dp, float* ws) {
    int d = threadIdx.x;
    int b = blockIdx.x, v = blockIdx.y;
    long m0 = (long)v * M1 + (long)b * FF;
    float A[DSTATE];
    #pragma unroll
    for (int s = 0; s < DSTATE; ++s) A[s] = ws[ANEG_OFF + d * DSTATE + s];
    float Dv = Dp[d];
    float h[DSTATE];
    #pragma unroll
    for (int s = 0; s < DSTATE; ++s) h[s] = 0.f;
    float* dtp = ws + DT_OFF;
    const float* xcp = ws + XC_OFF;
    const float* xzp = ws + XZ_OFF;
    const float* xd  = ws + EMB_OFF;   /* XDBL: [m][40] = dt_raw|Bs|Cs */
    for (int t = 0; t < FF; ++t) {
        long m = m0 + t;
        float dt = dtp[m * DI + d];
        float xc = xcp[m * DI + d];
        float z  = xzp[m * (2 * DI) + DI + d];
        const float* bc = xd + m * 40;
        float dtxc = dt * xc;
        float y = 0.f;
        #pragma unroll
        for (int s = 0; s < DSTATE; ++s) {
            float dA = expf(dt * A[s]);
            h[s] = fmaf(dA, h[s], dtxc * bc[8 + s]);
            y = fmaf(h[s], bc[24 + s], y);
        }
        float yy = fmaf(xc, Dv, y);
        float sg = 1.f / (1.f + expf(-z));
        dtp[m * DI + d] = yy * (z * sg);
    }
}

/* ---- per-row L2 norm of enc[v] reshaped (32, 32896): grid=(32,3) ---- */
__global__ __launch_bounds__(256) void k_norm(float* ws) {
    int i = blockIdx.x, v = blockIdx.y;
    const float* row = ws + ENC_OFF + (long)v * M1 * DM + (long)i * FF * DM;
    float acc = 0.f;
    for (int q = threadIdx.x; q < FF * DM; q += 256) { float xv = row[q]; acc = fmaf(xv, xv, acc); }
    __shared__ float red[256];
    red[threadIdx.x] = acc; __syncthreads();
    for (int s = 128; s > 0; s >>= 1) { if (threadIdx.x < s) red[threadIdx.x] += red[threadIdx.x + s]; __syncthreads(); }
    if (threadIdx.x == 0) ws[NRM_OFF + v * 32 + i] = sqrtf(red[0]);
}

/* ---- Gram dots enc0 · enc{1,2}: grid=(32 j, 32 i, 2 p) ---- */
__global__ __launch_bounds__(256) void k_sim(float* ws) {
    int j = blockIdx.x, i = blockIdx.y, p = blockIdx.z;
    const float* r1 = ws + ENC_OFF + (long)i * FF * DM;
    const float* r2 = ws + ENC_OFF + (long)(p + 1) * M1 * DM + (long)j * FF * DM;
    float acc = 0.f;
    for (int q = threadIdx.x; q < FF * DM; q += 256) acc = fmaf(r1[q], r2[q], acc);
    __shared__ float red[256];
    red[threadIdx.x] = acc; __syncthreads();
    for (int s = 128; s > 0; s >>= 1) { if (threadIdx.x < s) red[threadIdx.x] += red[threadIdx.x + s]; __syncthreads(); }
    if (threadIdx.x == 0) ws[SIM_OFF + p * 1024 + i * 32 + j] = red[0];
}

/* ---- NT-Xent losses, 1 block of 64 threads (p = tid>>5, i = tid&31) ---- */
__global__ void k_loss(float* ws, float* out) {
    int tid = threadIdx.x;
    int p = tid >> 5, i = tid & 31;
    float ni = ws[NRM_OFF + i];
    float sum = 0.f, pos = 0.f;
    for (int j = 0; j < 32; ++j) {
        float nj = ws[NRM_OFF + (p + 1) * 32 + j];
        float sim = ws[SIM_OFF + p * 1024 + i * 32 + j] / (ni * nj);
        float e = expf(sim * 2.0f);   /* /TEMP, TEMP=0.5 */
        sum += e;
        if (j == i) pos = e;
    }
    float l = -logf(pos / (sum - pos));
    for (int off = 32; off > 0; off >>= 1) l += __shfl_down(l, off, 64);
    if (tid == 0) out[(long)BB * WINL * CHN] = l / 32.f;
}

/* ---- recon loss: two-stage deterministic reduction ---- */
__global__ __launch_bounds__(256) void k_recon_part(float* ws) {
    float acc = 0.f;
    const float* sre = ws + SFRE_OFF;   /* variant 0 */
    const float* sim = ws + SFIM_OFF;
    const float* re  = ws + REAL_OFF;
    const float* im  = ws + IMAG_OFF;
    for (long q = (long)blockIdx.x * 256 + threadIdx.x; q < (long)M1 * CHN; q += 512L * 256) {
        float dr = sre[q] - re[q];
        float di = sim[q] - im[q];
        acc = fmaf(dr, dr, acc);
        acc = fmaf(di, di, acc);
    }
    __shared__ float red[256];
    red[threadIdx.x] = acc; __syncthreads();
    for (int s = 128; s > 0; s >>= 1) { if (threadIdx.x < s) red[threadIdx.x] += red[threadIdx.x + s]; __syncthreads(); }
    if (threadIdx.x == 0) ws[RED_OFF + blockIdx.x] = red[0];
}
__global__ __launch_bounds__(512) void k_recon_final(float* ws, float* out) {
    __shared__ float red[512];
    red[threadIdx.x] = ws[RED_OFF + threadIdx.x];
    __syncthreads();
    for (int s = 256; s > 0; s >>= 1) { if (threadIdx.x < s) red[threadIdx.x] += red[threadIdx.x + s]; __syncthreads(); }
    if (threadIdx.x == 0) out[(long)BB * WINL * CHN + 1] = red[0] / (float)((long)M1 * CHN);
}

/* ---- irfft (c2r: Im of DC/Nyquist ignored): block=(64 ch,4 t), grid=(128,32) ---- */
__global__ __launch_bounds__(256) void k_irfft(float* ws, float* __restrict__ out) {
    __shared__ float twc[512], tws[512];
    int tid = threadIdx.y * 64 + threadIdx.x;
    for (int q = tid; q < 512; q += 256) { twc[q] = ws[TW_OFF + q]; tws[q] = ws[TW_OFF + 512 + q]; }
    __syncthreads();
    int ch = threadIdx.x;
    int t  = blockIdx.x * 4 + threadIdx.y;
    int b  = blockIdx.y;
    const float* re = ws + REAL_OFF + (long)b * FF * CHN;
    const float* im = ws + IMAG_OFF + (long)b * FF * CHN;
    float nyq = re[256 * CHN + ch];
    float acc = re[ch] + ((t & 1) ? -nyq : nyq);
    int idx = t & 511;
    #pragma unroll 4
    for (int f = 1; f < 256; ++f) {
        acc = fmaf( 2.f * re[f * CHN + ch], twc[idx], acc);
        acc = fmaf(-2.f * im[f * CHN + ch], tws[idx], acc);
        idx = (idx + t) & 511;
    }
    out[((long)b * WINL + t) * CHN + ch] = acc * (1.f / 512.f);
}

extern "C" void kernel_launch(void* const* d_in, const int* in_sizes, int n_in,
                              void* d_out, int out_size, void* d_ws, size_t ws_size,
                              hipStream_t stream) {
    const float* x          = (const float*)d_in[0];
    const float* jitter     = (const float*)d_in[1];
    const float* u_mask     = (const float*)d_in[2];
    const float* fre_w      = (const float*)d_in[3];
    const float* fre_b      = (const float*)d_in[4];
    const float* in_proj_w  = (const float*)d_in[5];
    const float* conv_w     = (const float*)d_in[6];
    const float* conv_b     = (const float*)d_in[7];
    const float* xproj_w    = (const float*)d_in[8];
    const float* dtproj_w   = (const float*)d_in[9];
    const float* dtproj_b   = (const float*)d_in[10];
    const float* A_log      = (const float*)d_in[11];
    const float* D_param    = (const float*)d_in[12];
    const float* out_proj_w = (const float*)d_in[13];
    const float* getr_w     = (const float*)d_in[14];
    const float* getr_b     = (const float*)d_in[15];
    const float* geti_w     = (const float*)d_in[16];
    const float* geti_b     = (const float*)d_in[17];
    float* ws  = (float*)d_ws;
    float* out = (float*)d_out;

    k_init<<<18, 256, 0, stream>>>(ws, A_log);
    k_aug<<<4096, 256, 0, stream>>>(x, jitter, u_mask, ws);
    k_dft<<<dim3(65, 32, 3), dim3(64, 4), 0, stream>>>(x, ws);

    /* embed: [Re||Im] @ fre_w + fre_b -> EMB */
    k_gemm<<<dim3(2, M3 / 4), dim3(64, 4), 0, stream>>>(
        ws + SFRE_OFF, CHN, CHN, ws + SFIM_OFF, CHN, CHN,
        fre_w, DM, fre_b, ws + EMB_OFF, DM, M3, DM, 1);

    /* in_proj: EMB @ in_proj_w -> XZ */
    k_gemm<<<dim3(8, M3 / 4), dim3(64, 4), 0, stream>>>(
        ws + EMB_OFF, DM, DM, nullptr, 0, 0,
        in_proj_w, 2 * DI, nullptr, ws + XZ_OFF, 2 * DI, M3, 2 * DI, 0);

    k_conv<<<dim3(FF, BB, 3), 256, 0, stream>>>(conv_w, conv_b, ws);

    /* xproj: XC @ xproj_w -> XDBL (in EMB region) */
    k_gemm<<<dim3(1, M3 / 4), dim3(64, 4), 0, stream>>>(
        ws + XC_OFF, DI, DI, nullptr, 0, 0,
        xproj_w, 40, nullptr, ws + EMB_OFF, 40, M3, 40, 0);

    /* dtproj + softplus: XDBL[:, :8] @ dtproj_w + b -> DT */
    k_gemm<<<dim3(4, M3 / 4), dim3(64, 4), 0, stream>>>(
        ws + EMB_OFF, 40, 8, nullptr, 0, 0,
        dtproj_w, DI, dtproj_b, ws + DT_OFF, DI, M3, DI, 2);

    k_scan<<<dim3(BB, 3), 256, 0, stream>>>(D_param, ws);

    /* out_proj: Y @ out_proj_w -> ENC */
    k_gemm<<<dim3(2, M3 / 4), dim3(64, 4), 0, stream>>>(
        ws + DT_OFF, DI, DI, nullptr, 0, 0,
        out_proj_w, DM, nullptr, ws + ENC_OFF, DM, M3, DM, 0);

    /* heads: enc0 @ getr_w/geti_w + b -> REAL/IMAG */
    k_gemm<<<dim3(1, M1 / 4), dim3(64, 4), 0, stream>>>(
        ws + ENC_OFF, DM, DM, nullptr, 0, 0,
        getr_w, CHN, getr_b, ws + REAL_OFF, CHN, M1, CHN, 1);
    k_gemm<<<dim3(1, M1 / 4), dim3(64, 4), 0, stream>>>(
        ws + ENC_OFF, DM, DM, nullptr, 0, 0,
        geti_w, CHN, geti_b, ws + IMAG_OFF, CHN, M1, CHN, 1);

    k_norm<<<dim3(32, 3), 256, 0, stream>>>(ws);
    k_sim<<<dim3(32, 32, 2), 256, 0, stream>>>(ws);
    k_loss<<<1, 64, 0, stream>>>(ws, out);
    k_recon_part<<<512, 256, 0, stream>>>(ws);
    k_recon_final<<<1, 512, 0, stream>>>(ws, out);
    k_irfft<<<dim3(WINL / 4, BB), dim3(64, 4), 0, stream>>>(ws, out);
}

// Round 2
// 959.848 us; speedup vs baseline: 1.4169x; 1.4169x over previous
//
#include <hip/hip_runtime.h>
#include <math.h>

#define BB 32
#define WINL 512
#define CHN 64
#define FF 257
#define DM 128
#define DI 256
#define DSTATE 16
#define M1 (BB*FF)        /* 8224  rows per variant */
#define M3 (3*M1)         /* 24672 rows total       */

/* ---- workspace layout (float offsets) ---- */
static const long TW_OFF   = 0;                                /* cos[512], sin[512] */
static const long ANEG_OFF = 1024;                             /* A = -exp(A_log), 256*16 */
static const long SIG_OFF  = 5120;                             /* coarse, fine signals: 2*B*WIN*CH */
static const long SFRE_OFF = SIG_OFF  + 2L*BB*WINL*CHN;        /* 3*M1*CHN */
static const long SFIM_OFF = SFRE_OFF + 3L*M1*CHN;
static const long EMB_OFF  = SFIM_OFF + 3L*M1*CHN;             /* 3*M1*DM; later reused as XDBL (3*M1*40) */
static const long XZ_OFF   = EMB_OFF  + 3L*M1*DM;              /* 3*M1*512 */
static const long XC_OFF   = XZ_OFF   + 3L*M1*2*DI;            /* 3*M1*256 */
static const long DT_OFF   = XC_OFF   + 3L*M1*DI;              /* 3*M1*256; scan overwrites in-place with y */
static const long ENC_OFF  = DT_OFF   + 3L*M1*DI;              /* 3*M1*128 */
static const long REAL_OFF = ENC_OFF  + 3L*M1*DM;              /* M1*64 */
static const long IMAG_OFF = REAL_OFF + 1L*M1*CHN;
static const long NRM_OFF  = IMAG_OFF + 1L*M1*CHN;             /* 3*32 norms */
static const long SIM_OFF  = NRM_OFF  + 128;                   /* 2*32*32 */
static const long RED_OFF  = SIM_OFF  + 2048;                  /* 512 partials */

/* ---- init: twiddles + A = -exp(A_log) ---- */
__global__ void k_init(float* ws, const float* __restrict__ A_log) {
    int i = blockIdx.x * 256 + threadIdx.x;
    if (i < 512) {
        double ang = (double)i * (3.14159265358979323846 / 256.0);
        ws[TW_OFF + i]       = (float)cos(ang);
        ws[TW_OFF + 512 + i] = (float)sin(ang);
    }
    int j = i - 512;
    if (j >= 0 && j < DI * DSTATE) ws[ANEG_OFF + j] = -expf(A_log[j]);
}

/* ---- augment: coarse = x*(u_mask>0.3), fine = x + 0.3*jitter ---- */
__global__ void k_aug(const float* __restrict__ x, const float* __restrict__ jit,
                      const float* __restrict__ um, float* ws) {
    long i = (long)blockIdx.x * 256 + threadIdx.x;
    if (i >= (long)BB * WINL * CHN) return;
    float xv = x[i];
    float m  = (um[i >> 6] > 0.3f) ? 1.f : 0.f;
    ws[SIG_OFF + i] = xv * m;
    ws[SIG_OFF + (long)BB * WINL * CHN + i] = fmaf(0.3f, jit[i], xv);
}

/* ---- direct rDFT, table-driven: block=(64 ch, 4 f) ---- */
__global__ __launch_bounds__(256) void k_dft(const float* __restrict__ x, float* ws) {
    __shared__ float twc[512], tws[512];
    int tid = threadIdx.y * 64 + threadIdx.x;
    for (int q = tid; q < 512; q += 256) { twc[q] = ws[TW_OFF + q]; tws[q] = ws[TW_OFF + 512 + q]; }
    __syncthreads();
    int ch = threadIdx.x;
    int f  = blockIdx.x * 4 + threadIdx.y;
    int b  = blockIdx.y, v = blockIdx.z;
    if (f >= FF) return;
    const float* src = (v == 0) ? x : (ws + SIG_OFF + (long)(v - 1) * BB * WINL * CHN);
    const float* col = src + (long)b * WINL * CHN + ch;
    float are = 0.f, aim = 0.f;
    int idx = 0;
    #pragma unroll 4
    for (int t = 0; t < WINL; ++t) {
        float s = col[(long)t * CHN];
        are = fmaf(s,  twc[idx], are);
        aim = fmaf(s, -tws[idx], aim);
        idx = (idx + f) & 511;
    }
    long m = (long)v * M1 + (long)b * FF + f;
    ws[SFRE_OFF + m * CHN + ch] = are;
    ws[SFIM_OFF + m * CHN + ch] = aim;
}

/* ================= tiled register-blocked GEMM =================
   C[m,n] = sum_k A[m,k]*B[k,n] (+bias)(+softplus)
   A split into A1 (cols 0..K1-1) and optional A2 (cols K1..K-1).
   128x128 tile / block of 256 threads, K-step 16, 8x8 micro-tile. */
__global__ __launch_bounds__(256) void k_gemm_t(
    const float* __restrict__ A1, int lda1, int K1,
    const float* __restrict__ A2, int lda2,
    const float* __restrict__ Bm, int ldb,
    const float* __restrict__ bias,
    float* __restrict__ C, int ldc, int M, int N, int K, int mode)
{
    __shared__ float As[16][132];   /* [k][m] transposed; 132-stride keeps 16B align + bank spread */
    __shared__ float Bs[16][132];   /* [k][n] */
    int tid = threadIdx.x;
    int tx = tid & 15, ty = tid >> 4;
    int m0 = blockIdx.y * 128, n0 = blockIdx.x * 128;
    float acc[8][8];
    #pragma unroll
    for (int i = 0; i < 8; ++i)
        #pragma unroll
        for (int j = 0; j < 8; ++j) acc[i][j] = 0.f;

    for (int k0 = 0; k0 < K; k0 += 16) {
        /* ---- stage A (128 rows x 16 k), transposed ---- */
        bool afull = (m0 + 128 <= M) && (k0 + 16 <= K1) && (A2 == nullptr || k0 + 16 <= K1);
        #pragma unroll
        for (int c = tid; c < 512; c += 256) {
            int row = c >> 2, kq = (c & 3) << 2;
            int m = m0 + row, kk = k0 + kq;
            float4 v;
            if (afull) {
                v = *(const float4*)&A1[(long)m * lda1 + kk];
            } else {
                float t0 = 0.f, t1 = 0.f, t2 = 0.f, t3 = 0.f;
                if (m < M) {
                    int k;
                    k = kk + 0; if (k < K) t0 = (k < K1) ? A1[(long)m * lda1 + k] : A2[(long)m * lda2 + (k - K1)];
                    k = kk + 1; if (k < K) t1 = (k < K1) ? A1[(long)m * lda1 + k] : A2[(long)m * lda2 + (k - K1)];
                    k = kk + 2; if (k < K) t2 = (k < K1) ? A1[(long)m * lda1 + k] : A2[(long)m * lda2 + (k - K1)];
                    k = kk + 3; if (k < K) t3 = (k < K1) ? A1[(long)m * lda1 + k] : A2[(long)m * lda2 + (k - K1)];
                }
                v = make_float4(t0, t1, t2, t3);
            }
            As[kq + 0][row] = v.x; As[kq + 1][row] = v.y;
            As[kq + 2][row] = v.z; As[kq + 3][row] = v.w;
        }
        /* ---- stage B (16 k x 128 n) ---- */
        #pragma unroll
        for (int c = tid; c < 512; c += 256) {
            int row = c >> 5, nq = (c & 31) << 2;
            int k = k0 + row, n = n0 + nq;
            float4 v = make_float4(0.f, 0.f, 0.f, 0.f);
            if (k < K) {
                if (n + 3 < N) {
                    v = *(const float4*)&Bm[(long)k * ldb + n];
                } else {
                    float t[4] = {0.f, 0.f, 0.f, 0.f};
                    #pragma unroll
                    for (int j = 0; j < 4; ++j) if (n + j < N) t[j] = Bm[(long)k * ldb + n + j];
                    v = make_float4(t[0], t[1], t[2], t[3]);
                }
            }
            *(float4*)&Bs[row][nq] = v;
        }
        __syncthreads();
        #pragma unroll
        for (int k = 0; k < 16; ++k) {
            float4 a0 = *(const float4*)&As[k][(ty << 3)];
            float4 a1 = *(const float4*)&As[k][(ty << 3) + 4];
            float4 b0 = *(const float4*)&Bs[k][(tx << 3)];
            float4 b1 = *(const float4*)&Bs[k][(tx << 3) + 4];
            float av[8] = {a0.x, a0.y, a0.z, a0.w, a1.x, a1.y, a1.z, a1.w};
            float bv[8] = {b0.x, b0.y, b0.z, b0.w, b1.x, b1.y, b1.z, b1.w};
            #pragma unroll
            for (int i = 0; i < 8; ++i)
                #pragma unroll
                for (int j = 0; j < 8; ++j)
                    acc[i][j] = fmaf(av[i], bv[j], acc[i][j]);
        }
        __syncthreads();
    }
    /* ---- epilogue ---- */
    #pragma unroll
    for (int i = 0; i < 8; ++i) {
        int m = m0 + (ty << 3) + i;
        if (m >= M) break;
        #pragma unroll
        for (int j = 0; j < 8; ++j) {
            int n = n0 + (tx << 3) + j;
            if (n >= N) continue;
            float v = acc[i][j];
            if (mode >= 1) v += bias[n];
            if (mode == 2) v = (v > 20.f) ? v : log1pf(expf(v));
            C[(long)m * ldc + n] = v;
        }
    }
}

/* ---- depthwise causal conv (K=4) + SiLU: block=256 d, grid=(257,32,3) ---- */
__global__ __launch_bounds__(256) void k_conv(const float* __restrict__ cw,
                                              const float* __restrict__ cb, float* ws) {
    int d = threadIdx.x;
    int t = blockIdx.x, b = blockIdx.y, v = blockIdx.z;
    long m0 = (long)v * M1 + (long)b * FF;
    const float* xz = ws + XZ_OFF;
    float acc = cb[d];
    #pragma unroll
    for (int k = 0; k < 4; ++k) {
        int tt = t - 3 + k;
        if (tt >= 0) acc = fmaf(cw[d * 4 + k], xz[(m0 + tt) * (2 * DI) + d], acc);
    }
    float sg = 1.f / (1.f + expf(-acc));
    ws[XC_OFF + (m0 + t) * DI + d] = acc * sg;
}

/* ---- selective scan, fused dA/dBu + epilogue (y+xc*D)*silu(z), in-place over dt ---- */
__global__ __launch_bounds__(256) void k_scan(const float* __restrict__ Dp, float* ws) {
    int d = threadIdx.x;
    int b = blockIdx.x, v = blockIdx.y;
    long m0 = (long)v * M1 + (long)b * FF;
    float A[DSTATE];
    #pragma unroll
    for (int s = 0; s < DSTATE; ++s) A[s] = ws[ANEG_OFF + d * DSTATE + s];
    float Dv = Dp[d];
    float h[DSTATE];
    #pragma unroll
    for (int s = 0; s < DSTATE; ++s) h[s] = 0.f;
    float* dtp = ws + DT_OFF;
    const float* xcp = ws + XC_OFF;
    const float* xzp = ws + XZ_OFF;
    const float* xd  = ws + EMB_OFF;   /* XDBL: [m][40] = dt_raw|Bs|Cs */
    for (int t = 0; t < FF; ++t) {
        long m = m0 + t;
        float dt = dtp[m * DI + d];
        float xc = xcp[m * DI + d];
        float z  = xzp[m * (2 * DI) + DI + d];
        const float* bc = xd + m * 40;
        float dtxc = dt * xc;
        float y = 0.f;
        #pragma unroll
        for (int s = 0; s < DSTATE; ++s) {
            float dA = expf(dt * A[s]);
            h[s] = fmaf(dA, h[s], dtxc * bc[8 + s]);
            y = fmaf(h[s], bc[24 + s], y);
        }
        float yy = fmaf(xc, Dv, y);
        float sg = 1.f / (1.f + expf(-z));
        dtp[m * DI + d] = yy * (z * sg);
    }
}

/* ---- per-row L2 norm of enc[v] reshaped (32, 32896): grid=(32,3) ---- */
__global__ __launch_bounds__(256) void k_norm(float* ws) {
    int i = blockIdx.x, v = blockIdx.y;
    const float* row = ws + ENC_OFF + (long)v * M1 * DM + (long)i * FF * DM;
    float acc = 0.f;
    for (int q = threadIdx.x; q < FF * DM; q += 256) { float xv = row[q]; acc = fmaf(xv, xv, acc); }
    __shared__ float red[256];
    red[threadIdx.x] = acc; __syncthreads();
    for (int s = 128; s > 0; s >>= 1) { if (threadIdx.x < s) red[threadIdx.x] += red[threadIdx.x + s]; __syncthreads(); }
    if (threadIdx.x == 0) ws[NRM_OFF + v * 32 + i] = sqrtf(red[0]);
}

/* ---- Gram dots enc0 · enc{1,2}: grid=(32 j, 32 i, 2 p) ---- */
__global__ __launch_bounds__(256) void k_sim(float* ws) {
    int j = blockIdx.x, i = blockIdx.y, p = blockIdx.z;
    const float* r1 = ws + ENC_OFF + (long)i * FF * DM;
    const float* r2 = ws + ENC_OFF + (long)(p + 1) * M1 * DM + (long)j * FF * DM;
    float acc = 0.f;
    for (int q = threadIdx.x; q < FF * DM; q += 256) acc = fmaf(r1[q], r2[q], acc);
    __shared__ float red[256];
    red[threadIdx.x] = acc; __syncthreads();
    for (int s = 128; s > 0; s >>= 1) { if (threadIdx.x < s) red[threadIdx.x] += red[threadIdx.x + s]; __syncthreads(); }
    if (threadIdx.x == 0) ws[SIM_OFF + p * 1024 + i * 32 + j] = red[0];
}

/* ---- NT-Xent losses, 1 block of 64 threads (p = tid>>5, i = tid&31) ---- */
__global__ void k_loss(float* ws, float* out) {
    int tid = threadIdx.x;
    int p = tid >> 5, i = tid & 31;
    float ni = ws[NRM_OFF + i];
    float sum = 0.f, pos = 0.f;
    for (int j = 0; j < 32; ++j) {
        float nj = ws[NRM_OFF + (p + 1) * 32 + j];
        float sim = ws[SIM_OFF + p * 1024 + i * 32 + j] / (ni * nj);
        float e = expf(sim * 2.0f);   /* /TEMP, TEMP=0.5 */
        sum += e;
        if (j == i) pos = e;
    }
    float l = -logf(pos / (sum - pos));
    for (int off = 32; off > 0; off >>= 1) l += __shfl_down(l, off, 64);
    if (tid == 0) out[(long)BB * WINL * CHN] = l / 32.f;
}

/* ---- recon loss: two-stage deterministic reduction ---- */
__global__ __launch_bounds__(256) void k_recon_part(float* ws) {
    float acc = 0.f;
    const float* sre = ws + SFRE_OFF;   /* variant 0 */
    const float* sim = ws + SFIM_OFF;
    const float* re  = ws + REAL_OFF;
    const float* im  = ws + IMAG_OFF;
    for (long q = (long)blockIdx.x * 256 + threadIdx.x; q < (long)M1 * CHN; q += 512L * 256) {
        float dr = sre[q] - re[q];
        float di = sim[q] - im[q];
        acc = fmaf(dr, dr, acc);
        acc = fmaf(di, di, acc);
    }
    __shared__ float red[256];
    red[threadIdx.x] = acc; __syncthreads();
    for (int s = 128; s > 0; s >>= 1) { if (threadIdx.x < s) red[threadIdx.x] += red[threadIdx.x + s]; __syncthreads(); }
    if (threadIdx.x == 0) ws[RED_OFF + blockIdx.x] = red[0];
}
__global__ __launch_bounds__(512) void k_recon_final(float* ws, float* out) {
    __shared__ float red[512];
    red[threadIdx.x] = ws[RED_OFF + threadIdx.x];
    __syncthreads();
    for (int s = 256; s > 0; s >>= 1) { if (threadIdx.x < s) red[threadIdx.x] += red[threadIdx.x + s]; __syncthreads(); }
    if (threadIdx.x == 0) out[(long)BB * WINL * CHN + 1] = red[0] / (float)((long)M1 * CHN);
}

/* ---- irfft (c2r: Im of DC/Nyquist ignored): block=(64 ch,4 t), grid=(128,32) ---- */
__global__ __launch_bounds__(256) void k_irfft(float* ws, float* __restrict__ out) {
    __shared__ float twc[512], tws[512];
    int tid = threadIdx.y * 64 + threadIdx.x;
    for (int q = tid; q < 512; q += 256) { twc[q] = ws[TW_OFF + q]; tws[q] = ws[TW_OFF + 512 + q]; }
    __syncthreads();
    int ch = threadIdx.x;
    int t  = blockIdx.x * 4 + threadIdx.y;
    int b  = blockIdx.y;
    const float* re = ws + REAL_OFF + (long)b * FF * CHN;
    const float* im = ws + IMAG_OFF + (long)b * FF * CHN;
    float nyq = re[256 * CHN + ch];
    float acc = re[ch] + ((t & 1) ? -nyq : nyq);
    int idx = t & 511;
    #pragma unroll 4
    for (int f = 1; f < 256; ++f) {
        acc = fmaf( 2.f * re[f * CHN + ch], twc[idx], acc);
        acc = fmaf(-2.f * im[f * CHN + ch], tws[idx], acc);
        idx = (idx + t) & 511;
    }
    out[((long)b * WINL + t) * CHN + ch] = acc * (1.f / 512.f);
}

extern "C" void kernel_launch(void* const* d_in, const int* in_sizes, int n_in,
                              void* d_out, int out_size, void* d_ws, size_t ws_size,
                              hipStream_t stream) {
    const float* x          = (const float*)d_in[0];
    const float* jitter     = (const float*)d_in[1];
    const float* u_mask     = (const float*)d_in[2];
    const float* fre_w      = (const float*)d_in[3];
    const float* fre_b      = (const float*)d_in[4];
    const float* in_proj_w  = (const float*)d_in[5];
    const float* conv_w     = (const float*)d_in[6];
    const float* conv_b     = (const float*)d_in[7];
    const float* xproj_w    = (const float*)d_in[8];
    const float* dtproj_w   = (const float*)d_in[9];
    const float* dtproj_b   = (const float*)d_in[10];
    const float* A_log      = (const float*)d_in[11];
    const float* D_param    = (const float*)d_in[12];
    const float* out_proj_w = (const float*)d_in[13];
    const float* getr_w     = (const float*)d_in[14];
    const float* getr_b     = (const float*)d_in[15];
    const float* geti_w     = (const float*)d_in[16];
    const float* geti_b     = (const float*)d_in[17];
    float* ws  = (float*)d_ws;
    float* out = (float*)d_out;

    const int GY3 = (M3 + 127) / 128;   /* 193 */
    const int GY1 = (M1 + 127) / 128;   /* 65  */

    k_init<<<18, 256, 0, stream>>>(ws, A_log);
    k_aug<<<4096, 256, 0, stream>>>(x, jitter, u_mask, ws);
    k_dft<<<dim3(65, 32, 3), dim3(64, 4), 0, stream>>>(x, ws);

    /* embed: [Re||Im] @ fre_w + fre_b -> EMB */
    k_gemm_t<<<dim3(1, GY3), 256, 0, stream>>>(
        ws + SFRE_OFF, CHN, CHN, ws + SFIM_OFF, CHN,
        fre_w, DM, fre_b, ws + EMB_OFF, DM, M3, DM, 2 * CHN, 1);

    /* in_proj: EMB @ in_proj_w -> XZ */
    k_gemm_t<<<dim3(4, GY3), 256, 0, stream>>>(
        ws + EMB_OFF, DM, DM, nullptr, 0,
        in_proj_w, 2 * DI, nullptr, ws + XZ_OFF, 2 * DI, M3, 2 * DI, DM, 0);

    k_conv<<<dim3(FF, BB, 3), 256, 0, stream>>>(conv_w, conv_b, ws);

    /* xproj: XC @ xproj_w -> XDBL (in EMB region) */
    k_gemm_t<<<dim3(1, GY3), 256, 0, stream>>>(
        ws + XC_OFF, DI, DI, nullptr, 0,
        xproj_w, 40, nullptr, ws + EMB_OFF, 40, M3, 40, DI, 0);

    /* dtproj + softplus: XDBL[:, :8] @ dtproj_w + b -> DT */
    k_gemm_t<<<dim3(2, GY3), 256, 0, stream>>>(
        ws + EMB_OFF, 40, 8, nullptr, 0,
        dtproj_w, DI, dtproj_b, ws + DT_OFF, DI, M3, DI, 8, 2);

    k_scan<<<dim3(BB, 3), 256, 0, stream>>>(D_param, ws);

    /* out_proj: Y @ out_proj_w -> ENC */
    k_gemm_t<<<dim3(1, GY3), 256, 0, stream>>>(
        ws + DT_OFF, DI, DI, nullptr, 0,
        out_proj_w, DM, nullptr, ws + ENC_OFF, DM, M3, DM, DI, 0);

    /* heads: enc0 @ getr_w/geti_w + b -> REAL/IMAG */
    k_gemm_t<<<dim3(1, GY1), 256, 0, stream>>>(
        ws + ENC_OFF, DM, DM, nullptr, 0,
        getr_w, CHN, getr_b, ws + REAL_OFF, CHN, M1, CHN, DM, 1);
    k_gemm_t<<<dim3(1, GY1), 256, 0, stream>>>(
        ws + ENC_OFF, DM, DM, nullptr, 0,
        geti_w, CHN, geti_b, ws + IMAG_OFF, CHN, M1, CHN, DM, 1);

    k_norm<<<dim3(32, 3), 256, 0, stream>>>(ws);
    k_sim<<<dim3(32, 32, 2), 256, 0, stream>>>(ws);
    k_loss<<<1, 64, 0, stream>>>(ws, out);
    k_recon_part<<<512, 256, 0, stream>>>(ws);
    k_recon_final<<<1, 512, 0, stream>>>(ws, out);
    k_irfft<<<dim3(WINL / 4, BB), dim3(64, 4), 0, stream>>>(ws, out);
}

// Round 3
// 806.417 us; speedup vs baseline: 1.6865x; 1.1903x over previous
//
#include <hip/hip_runtime.h>
#include <math.h>

#define BB 32
#define WINL 512
#define CHN 64
#define FF 257
#define DM 128
#define DI 256
#define DSTATE 16
#define M1 (BB*FF)        /* 8224  rows per variant */
#define M3 (3*M1)         /* 24672 rows total       */
#define NC 8              /* scan time-chunks */
#define CS 33             /* chunk size (last = 26) */
#define LOG2E 1.4426950408889634f

/* ---- workspace layout (float offsets) ---- */
static const long TW_OFF   = 0;                                /* cos[512], sin[512] */
static const long ANEG_OFF = 1024;                             /* A2 = -exp(A_log)*log2e, 256*16 */
static const long SIG_OFF  = 5120;                             /* coarse, fine signals: 2*B*WIN*CH */
static const long SFRE_OFF = SIG_OFF  + 2L*BB*WINL*CHN;        /* 3*M1*CHN */
static const long SFIM_OFF = SFRE_OFF + 3L*M1*CHN;
static const long EMB_OFF  = SFIM_OFF + 3L*M1*CHN;             /* 3*M1*DM; later reused as XDBL (3*M1*40) */
static const long XZ_OFF   = EMB_OFF  + 3L*M1*DM;              /* 3*M1*512 */
static const long XC_OFF   = XZ_OFF   + 3L*M1*2*DI;            /* 3*M1*256 */
static const long DT_OFF   = XC_OFF   + 3L*M1*DI;              /* 3*M1*256; scan overwrites in-place with y */
static const long ENC_OFF  = DT_OFF   + 3L*M1*DI;              /* 3*M1*128 */
static const long REAL_OFF = ENC_OFF  + 3L*M1*DM;              /* M1*64 */
static const long IMAG_OFF = REAL_OFF + 1L*M1*CHN;
static const long NRM_OFF  = IMAG_OFF + 1L*M1*CHN;             /* 3*32 norms */
static const long SIM_OFF  = NRM_OFF  + 128;                   /* 2*32*32 */
static const long RED_OFF  = SIM_OFF  + 2048;                  /* 512 partials */
/* scan scratch, borrowed: HEND/HIN in ENC region (written only later by
   out_proj), SUMDT in SIG region (free after k_dft).
   HEND: [v][b][c][s][d] = 3*32*8*16*256 = 3.146M floats <= ENC 3.158M. */
static const long HEND_OFF  = ENC_OFF;
static const long SUMDT_OFF = SIG_OFF;

/* ---- init: twiddles + A2 = -exp(A_log)*log2e ---- */
__global__ void k_init(float* ws, const float* __restrict__ A_log) {
    int i = blockIdx.x * 256 + threadIdx.x;
    if (i < 512) {
        double ang = (double)i * (3.14159265358979323846 / 256.0);
        ws[TW_OFF + i]       = (float)cos(ang);
        ws[TW_OFF + 512 + i] = (float)sin(ang);
    }
    int j = i - 512;
    if (j >= 0 && j < DI * DSTATE) ws[ANEG_OFF + j] = -expf(A_log[j]) * LOG2E;
}

/* ---- augment: coarse = x*(u_mask>0.3), fine = x + 0.3*jitter ---- */
__global__ void k_aug(const float* __restrict__ x, const float* __restrict__ jit,
                      const float* __restrict__ um, float* ws) {
    long i = (long)blockIdx.x * 256 + threadIdx.x;
    if (i >= (long)BB * WINL * CHN) return;
    float xv = x[i];
    float m  = (um[i >> 6] > 0.3f) ? 1.f : 0.f;
    ws[SIG_OFF + i] = xv * m;
    ws[SIG_OFF + (long)BB * WINL * CHN + i] = fmaf(0.3f, jit[i], xv);
}

/* ---- direct rDFT, table-driven: block=(64 ch, 4 f) ---- */
__global__ __launch_bounds__(256) void k_dft(const float* __restrict__ x, float* ws) {
    __shared__ float twc[512], tws[512];
    int tid = threadIdx.y * 64 + threadIdx.x;
    for (int q = tid; q < 512; q += 256) { twc[q] = ws[TW_OFF + q]; tws[q] = ws[TW_OFF + 512 + q]; }
    __syncthreads();
    int ch = threadIdx.x;
    int f  = blockIdx.x * 4 + threadIdx.y;
    int b  = blockIdx.y, v = blockIdx.z;
    if (f >= FF) return;
    const float* src = (v == 0) ? x : (ws + SIG_OFF + (long)(v - 1) * BB * WINL * CHN);
    const float* col = src + (long)b * WINL * CHN + ch;
    float are = 0.f, aim = 0.f;
    int idx = 0;
    #pragma unroll 4
    for (int t = 0; t < WINL; ++t) {
        float s = col[(long)t * CHN];
        are = fmaf(s,  twc[idx], are);
        aim = fmaf(s, -tws[idx], aim);
        idx = (idx + f) & 511;
    }
    long m = (long)v * M1 + (long)b * FF + f;
    ws[SFRE_OFF + m * CHN + ch] = are;
    ws[SFIM_OFF + m * CHN + ch] = aim;
}

/* NOTE: k_aug writes SIG, k_dft reads SIG; SUMDT (scan) reuses SIG only
   after k_dft is done — stream-ordered, safe. */

/* ================= tiled register-blocked GEMM =================
   C[m,n] = sum_k A[m,k]*B[k,n] (+bias)(+softplus)
   A split into A1 (cols 0..K1-1) and optional A2 (cols K1..K-1).
   128x128 tile / block of 256 threads, K-step 16, 8x8 micro-tile. */
__global__ __launch_bounds__(256) void k_gemm_t(
    const float* __restrict__ A1, int lda1, int K1,
    const float* __restrict__ A2, int lda2,
    const float* __restrict__ Bm, int ldb,
    const float* __restrict__ bias,
    float* __restrict__ C, int ldc, int M, int N, int K, int mode)
{
    __shared__ float As[16][132];
    __shared__ float Bs[16][132];
    int tid = threadIdx.x;
    int tx = tid & 15, ty = tid >> 4;
    int m0 = blockIdx.y * 128, n0 = blockIdx.x * 128;
    float acc[8][8];
    #pragma unroll
    for (int i = 0; i < 8; ++i)
        #pragma unroll
        for (int j = 0; j < 8; ++j) acc[i][j] = 0.f;

    for (int k0 = 0; k0 < K; k0 += 16) {
        bool afull = (m0 + 128 <= M) && (k0 + 16 <= K1);
        #pragma unroll
        for (int c = tid; c < 512; c += 256) {
            int row = c >> 2, kq = (c & 3) << 2;
            int m = m0 + row, kk = k0 + kq;
            float4 v;
            if (afull) {
                v = *(const float4*)&A1[(long)m * lda1 + kk];
            } else {
                float t0 = 0.f, t1 = 0.f, t2 = 0.f, t3 = 0.f;
                if (m < M) {
                    int k;
                    k = kk + 0; if (k < K) t0 = (k < K1) ? A1[(long)m * lda1 + k] : A2[(long)m * lda2 + (k - K1)];
                    k = kk + 1; if (k < K) t1 = (k < K1) ? A1[(long)m * lda1 + k] : A2[(long)m * lda2 + (k - K1)];
                    k = kk + 2; if (k < K) t2 = (k < K1) ? A1[(long)m * lda1 + k] : A2[(long)m * lda2 + (k - K1)];
                    k = kk + 3; if (k < K) t3 = (k < K1) ? A1[(long)m * lda1 + k] : A2[(long)m * lda2 + (k - K1)];
                }
                v = make_float4(t0, t1, t2, t3);
            }
            As[kq + 0][row] = v.x; As[kq + 1][row] = v.y;
            As[kq + 2][row] = v.z; As[kq + 3][row] = v.w;
        }
        #pragma unroll
        for (int c = tid; c < 512; c += 256) {
            int row = c >> 5, nq = (c & 31) << 2;
            int k = k0 + row, n = n0 + nq;
            float4 v = make_float4(0.f, 0.f, 0.f, 0.f);
            if (k < K) {
                if (n + 3 < N) {
                    v = *(const float4*)&Bm[(long)k * ldb + n];
                } else {
                    float t[4] = {0.f, 0.f, 0.f, 0.f};
                    #pragma unroll
                    for (int j = 0; j < 4; ++j) if (n + j < N) t[j] = Bm[(long)k * ldb + n + j];
                    v = make_float4(t[0], t[1], t[2], t[3]);
                }
            }
            *(float4*)&Bs[row][nq] = v;
        }
        __syncthreads();
        #pragma unroll
        for (int k = 0; k < 16; ++k) {
            float4 a0 = *(const float4*)&As[k][(ty << 3)];
            float4 a1 = *(const float4*)&As[k][(ty << 3) + 4];
            float4 b0 = *(const float4*)&Bs[k][(tx << 3)];
            float4 b1 = *(const float4*)&Bs[k][(tx << 3) + 4];
            float av[8] = {a0.x, a0.y, a0.z, a0.w, a1.x, a1.y, a1.z, a1.w};
            float bv[8] = {b0.x, b0.y, b0.z, b0.w, b1.x, b1.y, b1.z, b1.w};
            #pragma unroll
            for (int i = 0; i < 8; ++i)
                #pragma unroll
                for (int j = 0; j < 8; ++j)
                    acc[i][j] = fmaf(av[i], bv[j], acc[i][j]);
        }
        __syncthreads();
    }
    #pragma unroll
    for (int i = 0; i < 8; ++i) {
        int m = m0 + (ty << 3) + i;
        if (m >= M) break;
        #pragma unroll
        for (int j = 0; j < 8; ++j) {
            int n = n0 + (tx << 3) + j;
            if (n >= N) continue;
            float v = acc[i][j];
            if (mode >= 1) v += bias[n];
            if (mode == 2) v = (v > 20.f) ? v : log1pf(expf(v));
            C[(long)m * ldc + n] = v;
        }
    }
}

/* ---- depthwise causal conv (K=4) + SiLU: block=256 d, grid=(257,32,3) ---- */
__global__ __launch_bounds__(256) void k_conv(const float* __restrict__ cw,
                                              const float* __restrict__ cb, float* ws) {
    int d = threadIdx.x;
    int t = blockIdx.x, b = blockIdx.y, v = blockIdx.z;
    long m0 = (long)v * M1 + (long)b * FF;
    const float* xz = ws + XZ_OFF;
    float acc = cb[d];
    #pragma unroll
    for (int k = 0; k < 4; ++k) {
        int tt = t - 3 + k;
        if (tt >= 0) acc = fmaf(cw[d * 4 + k], xz[(m0 + tt) * (2 * DI) + d], acc);
    }
    float sg = 1.f / (1.f + exp2f(-LOG2E * acc));
    ws[XC_OFF + (m0 + t) * DI + d] = acc * sg;
}

/* ======== chunked selective scan: 3 passes over NC=8 time chunks ========
   h_t = exp(dt*A)*h + dt*xc*B;  y_t = <h_t, C>;  out = (y+xc*D)*silu(z). */

/* pass 1: per-chunk scan from h=0; store h_end + sum(dt). grid=(NC,BB,3) */
__global__ __launch_bounds__(256) void k_scan_part(float* ws) {
    int d = threadIdx.x;
    int c = blockIdx.x, b = blockIdx.y, v = blockIdx.z;
    long m0 = (long)v * M1 + (long)b * FF;
    int t0 = c * CS, t1 = (t0 + CS < FF) ? t0 + CS : FF;
    float A2[DSTATE], h[DSTATE];
    #pragma unroll
    for (int s = 0; s < DSTATE; ++s) { A2[s] = ws[ANEG_OFF + d * DSTATE + s]; h[s] = 0.f; }
    float sumdt = 0.f;
    const float* dtp = ws + DT_OFF;
    const float* xcp = ws + XC_OFF;
    const float* xd  = ws + EMB_OFF;
    for (int t = t0; t < t1; ++t) {
        long m = m0 + t;
        float dt = dtp[m * DI + d];
        float xc = xcp[m * DI + d];
        const float* bc = xd + m * 40;
        sumdt += dt;
        float dtxc = dt * xc;
        #pragma unroll
        for (int s = 0; s < DSTATE; ++s) {
            float dA = exp2f(dt * A2[s]);
            h[s] = fmaf(dA, h[s], dtxc * bc[8 + s]);
        }
    }
    long cb = ((long)v * BB + b) * NC + c;
    #pragma unroll
    for (int s = 0; s < DSTATE; ++s) ws[HEND_OFF + (cb * DSTATE + s) * 256 + d] = h[s];
    ws[SUMDT_OFF + cb * 256 + d] = sumdt;
}

/* pass 2: sequential fix-up across chunks; HEND -> HIN in place. grid=(BB,3) */
__global__ __launch_bounds__(256) void k_scan_fix(float* ws) {
    int d = threadIdx.x;
    int b = blockIdx.x, v = blockIdx.y;
    float A2[DSTATE], prev[DSTATE];
    #pragma unroll
    for (int s = 0; s < DSTATE; ++s) { A2[s] = ws[ANEG_OFF + d * DSTATE + s]; prev[s] = 0.f; }
    long cb0 = ((long)v * BB + b) * NC;
    for (int c = 0; c < NC; ++c) {
        long cb = cb0 + c;
        float sd = ws[SUMDT_OFF + cb * 256 + d];
        #pragma unroll
        for (int s = 0; s < DSTATE; ++s) {
            long idx = HEND_OFF + (cb * DSTATE + s) * 256 + d;
            float he = ws[idx];
            ws[idx] = prev[s];
            prev[s] = fmaf(exp2f(A2[s] * sd), prev[s], he);
        }
    }
}

/* pass 3: re-scan chunk from HIN, emit outputs with fused epilogue. grid=(NC,BB,3) */
__global__ __launch_bounds__(256) void k_scan_out(const float* __restrict__ Dp, float* ws) {
    int d = threadIdx.x;
    int c = blockIdx.x, b = blockIdx.y, v = blockIdx.z;
    long m0 = (long)v * M1 + (long)b * FF;
    int t0 = c * CS, t1 = (t0 + CS < FF) ? t0 + CS : FF;
    long cb = ((long)v * BB + b) * NC + c;
    float A2[DSTATE], h[DSTATE];
    #pragma unroll
    for (int s = 0; s < DSTATE; ++s) {
        A2[s] = ws[ANEG_OFF + d * DSTATE + s];
        h[s]  = ws[HEND_OFF + (cb * DSTATE + s) * 256 + d];   /* = h_in */
    }
    float Dv = Dp[d];
    float* dtp = ws + DT_OFF;
    const float* xcp = ws + XC_OFF;
    const float* xzp = ws + XZ_OFF;
    const float* xd  = ws + EMB_OFF;
    for (int t = t0; t < t1; ++t) {
        long m = m0 + t;
        float dt = dtp[m * DI + d];
        float xc = xcp[m * DI + d];
        float z  = xzp[m * (2 * DI) + DI + d];
        const float* bc = xd + m * 40;
        float dtxc = dt * xc;
        float y = 0.f;
        #pragma unroll
        for (int s = 0; s < DSTATE; ++s) {
            float dA = exp2f(dt * A2[s]);
            h[s] = fmaf(dA, h[s], dtxc * bc[8 + s]);
            y = fmaf(h[s], bc[24 + s], y);
        }
        float yy = fmaf(xc, Dv, y);
        float sg = 1.f / (1.f + exp2f(-LOG2E * z));
        dtp[m * DI + d] = yy * (z * sg);
    }
}

/* ---- per-row L2 norm of enc[v] reshaped (32, 32896): grid=(32,3) ---- */
__global__ __launch_bounds__(256) void k_norm(float* ws) {
    int i = blockIdx.x, v = blockIdx.y;
    const float* row = ws + ENC_OFF + (long)v * M1 * DM + (long)i * FF * DM;
    float acc = 0.f;
    for (int q = threadIdx.x; q < FF * DM; q += 256) { float xv = row[q]; acc = fmaf(xv, xv, acc); }
    __shared__ float red[256];
    red[threadIdx.x] = acc; __syncthreads();
    for (int s = 128; s > 0; s >>= 1) { if (threadIdx.x < s) red[threadIdx.x] += red[threadIdx.x + s]; __syncthreads(); }
    if (threadIdx.x == 0) ws[NRM_OFF + v * 32 + i] = sqrtf(red[0]);
}

/* ---- Gram dots enc0 · enc{1,2}: grid=(32 j, 32 i, 2 p) ---- */
__global__ __launch_bounds__(256) void k_sim(float* ws) {
    int j = blockIdx.x, i = blockIdx.y, p = blockIdx.z;
    const float* r1 = ws + ENC_OFF + (long)i * FF * DM;
    const float* r2 = ws + ENC_OFF + (long)(p + 1) * M1 * DM + (long)j * FF * DM;
    float acc = 0.f;
    for (int q = threadIdx.x; q < FF * DM; q += 256) acc = fmaf(r1[q], r2[q], acc);
    __shared__ float red[256];
    red[threadIdx.x] = acc; __syncthreads();
    for (int s = 128; s > 0; s >>= 1) { if (threadIdx.x < s) red[threadIdx.x] += red[threadIdx.x + s]; __syncthreads(); }
    if (threadIdx.x == 0) ws[SIM_OFF + p * 1024 + i * 32 + j] = red[0];
}

/* ---- NT-Xent losses, 1 block of 64 threads (p = tid>>5, i = tid&31) ---- */
__global__ void k_loss(float* ws, float* out) {
    int tid = threadIdx.x;
    int p = tid >> 5, i = tid & 31;
    float ni = ws[NRM_OFF + i];
    float sum = 0.f, pos = 0.f;
    for (int j = 0; j < 32; ++j) {
        float nj = ws[NRM_OFF + (p + 1) * 32 + j];
        float sim = ws[SIM_OFF + p * 1024 + i * 32 + j] / (ni * nj);
        float e = expf(sim * 2.0f);   /* /TEMP, TEMP=0.5 */
        sum += e;
        if (j == i) pos = e;
    }
    float l = -logf(pos / (sum - pos));
    for (int off = 32; off > 0; off >>= 1) l += __shfl_down(l, off, 64);
    if (tid == 0) out[(long)BB * WINL * CHN] = l / 32.f;
}

/* ---- recon loss: two-stage deterministic reduction ---- */
__global__ __launch_bounds__(256) void k_recon_part(float* ws) {
    float acc = 0.f;
    const float* sre = ws + SFRE_OFF;   /* variant 0 */
    const float* sim = ws + SFIM_OFF;
    const float* re  = ws + REAL_OFF;
    const float* im  = ws + IMAG_OFF;
    for (long q = (long)blockIdx.x * 256 + threadIdx.x; q < (long)M1 * CHN; q += 512L * 256) {
        float dr = sre[q] - re[q];
        float di = sim[q] - im[q];
        acc = fmaf(dr, dr, acc);
        acc = fmaf(di, di, acc);
    }
    __shared__ float red[256];
    red[threadIdx.x] = acc; __syncthreads();
    for (int s = 128; s > 0; s >>= 1) { if (threadIdx.x < s) red[threadIdx.x] += red[threadIdx.x + s]; __syncthreads(); }
    if (threadIdx.x == 0) ws[RED_OFF + blockIdx.x] = red[0];
}
__global__ __launch_bounds__(512) void k_recon_final(float* ws, float* out) {
    __shared__ float red[512];
    red[threadIdx.x] = ws[RED_OFF + threadIdx.x];
    __syncthreads();
    for (int s = 256; s > 0; s >>= 1) { if (threadIdx.x < s) red[threadIdx.x] += red[threadIdx.x + s]; __syncthreads(); }
    if (threadIdx.x == 0) out[(long)BB * WINL * CHN + 1] = red[0] / (float)((long)M1 * CHN);
}

/* ---- irfft (c2r: Im of DC/Nyquist ignored): block=(64 ch,4 t), grid=(128,32) ---- */
__global__ __launch_bounds__(256) void k_irfft(float* ws, float* __restrict__ out) {
    __shared__ float twc[512], tws[512];
    int tid = threadIdx.y * 64 + threadIdx.x;
    for (int q = tid; q < 512; q += 256) { twc[q] = ws[TW_OFF + q]; tws[q] = ws[TW_OFF + 512 + q]; }
    __syncthreads();
    int ch = threadIdx.x;
    int t  = blockIdx.x * 4 + threadIdx.y;
    int b  = blockIdx.y;
    const float* re = ws + REAL_OFF + (long)b * FF * CHN;
    const float* im = ws + IMAG_OFF + (long)b * FF * CHN;
    float nyq = re[256 * CHN + ch];
    float acc = re[ch] + ((t & 1) ? -nyq : nyq);
    int idx = t & 511;
    #pragma unroll 4
    for (int f = 1; f < 256; ++f) {
        acc = fmaf( 2.f * re[f * CHN + ch], twc[idx], acc);
        acc = fmaf(-2.f * im[f * CHN + ch], tws[idx], acc);
        idx = (idx + t) & 511;
    }
    out[((long)b * WINL + t) * CHN + ch] = acc * (1.f / 512.f);
}

extern "C" void kernel_launch(void* const* d_in, const int* in_sizes, int n_in,
                              void* d_out, int out_size, void* d_ws, size_t ws_size,
                              hipStream_t stream) {
    const float* x          = (const float*)d_in[0];
    const float* jitter     = (const float*)d_in[1];
    const float* u_mask     = (const float*)d_in[2];
    const float* fre_w      = (const float*)d_in[3];
    const float* fre_b      = (const float*)d_in[4];
    const float* in_proj_w  = (const float*)d_in[5];
    const float* conv_w     = (const float*)d_in[6];
    const float* conv_b     = (const float*)d_in[7];
    const float* xproj_w    = (const float*)d_in[8];
    const float* dtproj_w   = (const float*)d_in[9];
    const float* dtproj_b   = (const float*)d_in[10];
    const float* A_log      = (const float*)d_in[11];
    const float* D_param    = (const float*)d_in[12];
    const float* out_proj_w = (const float*)d_in[13];
    const float* getr_w     = (const float*)d_in[14];
    const float* getr_b     = (const float*)d_in[15];
    const float* geti_w     = (const float*)d_in[16];
    const float* geti_b     = (const float*)d_in[17];
    float* ws  = (float*)d_ws;
    float* out = (float*)d_out;

    const int GY3 = (M3 + 127) / 128;   /* 193 */
    const int GY1 = (M1 + 127) / 128;   /* 65  */

    k_init<<<18, 256, 0, stream>>>(ws, A_log);
    k_aug<<<4096, 256, 0, stream>>>(x, jitter, u_mask, ws);
    k_dft<<<dim3(65, 32, 3), dim3(64, 4), 0, stream>>>(x, ws);

    /* embed: [Re||Im] @ fre_w + fre_b -> EMB */
    k_gemm_t<<<dim3(1, GY3), 256, 0, stream>>>(
        ws + SFRE_OFF, CHN, CHN, ws + SFIM_OFF, CHN,
        fre_w, DM, fre_b, ws + EMB_OFF, DM, M3, DM, 2 * CHN, 1);

    /* in_proj: EMB @ in_proj_w -> XZ */
    k_gemm_t<<<dim3(4, GY3), 256, 0, stream>>>(
        ws + EMB_OFF, DM, DM, nullptr, 0,
        in_proj_w, 2 * DI, nullptr, ws + XZ_OFF, 2 * DI, M3, 2 * DI, DM, 0);

    k_conv<<<dim3(FF, BB, 3), 256, 0, stream>>>(conv_w, conv_b, ws);

    /* xproj: XC @ xproj_w -> XDBL (in EMB region) */
    k_gemm_t<<<dim3(1, GY3), 256, 0, stream>>>(
        ws + XC_OFF, DI, DI, nullptr, 0,
        xproj_w, 40, nullptr, ws + EMB_OFF, 40, M3, 40, DI, 0);

    /* dtproj + softplus: XDBL[:, :8] @ dtproj_w + b -> DT */
    k_gemm_t<<<dim3(2, GY3), 256, 0, stream>>>(
        ws + EMB_OFF, 40, 8, nullptr, 0,
        dtproj_w, DI, dtproj_b, ws + DT_OFF, DI, M3, DI, 8, 2);

    /* chunked selective scan */
    k_scan_part<<<dim3(NC, BB, 3), 256, 0, stream>>>(ws);
    k_scan_fix<<<dim3(BB, 3), 256, 0, stream>>>(ws);
    k_scan_out<<<dim3(NC, BB, 3), 256, 0, stream>>>(D_param, ws);

    /* out_proj: Y @ out_proj_w -> ENC */
    k_gemm_t<<<dim3(1, GY3), 256, 0, stream>>>(
        ws + DT_OFF, DI, DI, nullptr, 0,
        out_proj_w, DM, nullptr, ws + ENC_OFF, DM, M3, DM, DI, 0);

    /* heads: enc0 @ getr_w/geti_w + b -> REAL/IMAG */
    k_gemm_t<<<dim3(1, GY1), 256, 0, stream>>>(
        ws + ENC_OFF, DM, DM, nullptr, 0,
        getr_w, CHN, getr_b, ws + REAL_OFF, CHN, M1, CHN, DM, 1);
    k_gemm_t<<<dim3(1, GY1), 256, 0, stream>>>(
        ws + ENC_OFF, DM, DM, nullptr, 0,
        geti_w, CHN, geti_b, ws + IMAG_OFF, CHN, M1, CHN, DM, 1);

    k_norm<<<dim3(32, 3), 256, 0, stream>>>(ws);
    k_sim<<<dim3(32, 32, 2), 256, 0, stream>>>(ws);
    k_loss<<<1, 64, 0, stream>>>(ws, out);
    k_recon_part<<<512, 256, 0, stream>>>(ws);
    k_recon_final<<<1, 512, 0, stream>>>(ws, out);
    k_irfft<<<dim3(WINL / 4, BB), dim3(64, 4), 0, stream>>>(ws, out);
}

// Round 4
// 626.247 us; speedup vs baseline: 2.1717x; 1.2877x over previous
//
#include <hip/hip_runtime.h>
#include <math.h>

#define BB 32
#define WINL 512
#define CHN 64
#define FF 257
#define DM 128
#define DI 256
#define DSTATE 16
#define M1 (BB*FF)        /* 8224  rows per variant */
#define M3 (3*M1)         /* 24672 rows total       */
#define NC 8              /* scan time-chunks */
#define CS 33             /* chunk size (last = 26) */
#define LOG2E 1.4426950408889634f

/* ---- workspace layout (float offsets) ---- */
static const long TW_OFF   = 0;                                /* cos[512], sin[512] */
static const long ANEG_OFF = 1024;                             /* A2 = -exp(A_log)*log2e, 256*16 */
static const long SIG_OFF  = 5120;                             /* coarse, fine signals: 2*B*WIN*CH */
static const long SFRE_OFF = SIG_OFF  + 2L*BB*WINL*CHN;        /* 3*M1*CHN */
static const long SFIM_OFF = SFRE_OFF + 3L*M1*CHN;
static const long EMB_OFF  = SFIM_OFF + 3L*M1*CHN;             /* 3*M1*DM; later reused as XDBL (3*M1*40) */
static const long XZ_OFF   = EMB_OFF  + 3L*M1*DM;              /* 3*M1*512 */
static const long XC_OFF   = XZ_OFF   + 3L*M1*2*DI;            /* 3*M1*256 */
static const long DT_OFF   = XC_OFF   + 3L*M1*DI;              /* 3*M1*256; scan overwrites in-place with y */
static const long ENC_OFF  = DT_OFF   + 3L*M1*DI;              /* 3*M1*128 */
static const long REAL_OFF = ENC_OFF  + 3L*M1*DM;              /* M1*64 */
static const long IMAG_OFF = REAL_OFF + 1L*M1*CHN;
static const long NRM_OFF  = IMAG_OFF + 1L*M1*CHN;             /* 3*32 norms */
static const long SIM_OFF  = NRM_OFF  + 128;                   /* 2*32*32 */
static const long RED_OFF  = SIM_OFF  + 2048;                  /* 512 partials */
/* scan scratch, borrowed: HEND/HIN in ENC region (written only later by
   out_proj), SUMDT in SIG region (free after k_dft). */
static const long HEND_OFF  = ENC_OFF;
static const long SUMDT_OFF = SIG_OFF;

/* ---- init: twiddles + A2 = -exp(A_log)*log2e ---- */
__global__ void k_init(float* ws, const float* __restrict__ A_log) {
    int i = blockIdx.x * 256 + threadIdx.x;
    if (i < 512) {
        double ang = (double)i * (3.14159265358979323846 / 256.0);
        ws[TW_OFF + i]       = (float)cos(ang);
        ws[TW_OFF + 512 + i] = (float)sin(ang);
    }
    int j = i - 512;
    if (j >= 0 && j < DI * DSTATE) ws[ANEG_OFF + j] = -expf(A_log[j]) * LOG2E;
}

/* ---- augment: coarse = x*(u_mask>0.3), fine = x + 0.3*jitter ---- */
__global__ void k_aug(const float* __restrict__ x, const float* __restrict__ jit,
                      const float* __restrict__ um, float* ws) {
    long i = (long)blockIdx.x * 256 + threadIdx.x;
    if (i >= (long)BB * WINL * CHN) return;
    float xv = x[i];
    float m  = (um[i >> 6] > 0.3f) ? 1.f : 0.f;
    ws[SIG_OFF + i] = xv * m;
    ws[SIG_OFF + (long)BB * WINL * CHN + i] = fmaf(0.3f, jit[i], xv);
}

/* ---- rDFT via radix-8 decimation in time ----
   thread (ch, g): E_r[g] = sum_u x[8u+r] w_512^{8gu}, r=0..7
   then S_{g+64k} = sum_r w_512^{(g+64k)r} E_r.  grid=(16,BB,3), block=(64,4). */
__global__ __launch_bounds__(256) void k_dft(const float* __restrict__ x, float* ws) {
    __shared__ float twc[512], tws[512];
    int tid = threadIdx.y * 64 + threadIdx.x;
    for (int q = tid; q < 512; q += 256) { twc[q] = ws[TW_OFF + q]; tws[q] = ws[TW_OFF + 512 + q]; }
    __syncthreads();
    int ch = threadIdx.x;
    int g  = blockIdx.x * 4 + threadIdx.y;   /* 0..63 */
    int b  = blockIdx.y, v = blockIdx.z;
    const float* src = (v == 0) ? x : (ws + SIG_OFF + (long)(v - 1) * BB * WINL * CHN);
    const float* col = src + (long)b * WINL * CHN + ch;
    float er[8], ei[8];
    #pragma unroll
    for (int r = 0; r < 8; ++r) { er[r] = 0.f; ei[r] = 0.f; }
    int idx = 0, step = (8 * g) & 511;
    for (int u = 0; u < 64; ++u) {
        float c = twc[idx], s = tws[idx];
        #pragma unroll
        for (int r = 0; r < 8; ++r) {
            float xv = col[(long)(8 * u + r) * CHN];
            er[r] = fmaf(xv,  c, er[r]);
            ei[r] = fmaf(xv, -s, ei[r]);
        }
        idx = (idx + step) & 511;
    }
    long mb = (long)v * M1 + (long)b * FF;
    for (int k = 0; k < 5; ++k) {
        int f = g + 64 * k;
        if (f > 256) break;              /* wave-uniform: g is per-wave */
        float sre = 0.f, sim = 0.f;
        int i2 = 0;
        #pragma unroll
        for (int r = 0; r < 8; ++r) {
            float c2 = twc[i2], s2 = tws[i2];
            sre += er[r] * c2 + ei[r] * s2;
            sim += ei[r] * c2 - er[r] * s2;
            i2 = (i2 + f) & 511;
        }
        long m = mb + f;
        ws[SFRE_OFF + m * CHN + ch] = sre;
        ws[SFIM_OFF + m * CHN + ch] = sim;
    }
}

/* ================= tiled register-blocked GEMM ================= */
__global__ __launch_bounds__(256) void k_gemm_t(
    const float* __restrict__ A1, int lda1, int K1,
    const float* __restrict__ A2, int lda2,
    const float* __restrict__ Bm, int ldb,
    const float* __restrict__ bias,
    float* __restrict__ C, int ldc, int M, int N, int K, int mode)
{
    __shared__ float As[16][132];
    __shared__ float Bs[16][132];
    int tid = threadIdx.x;
    int tx = tid & 15, ty = tid >> 4;
    int m0 = blockIdx.y * 128, n0 = blockIdx.x * 128;
    float acc[8][8];
    #pragma unroll
    for (int i = 0; i < 8; ++i)
        #pragma unroll
        for (int j = 0; j < 8; ++j) acc[i][j] = 0.f;

    for (int k0 = 0; k0 < K; k0 += 16) {
        bool afull = (m0 + 128 <= M) && (k0 + 16 <= K1);
        #pragma unroll
        for (int c = tid; c < 512; c += 256) {
            int row = c >> 2, kq = (c & 3) << 2;
            int m = m0 + row, kk = k0 + kq;
            float4 v;
            if (afull) {
                v = *(const float4*)&A1[(long)m * lda1 + kk];
            } else {
                float t0 = 0.f, t1 = 0.f, t2 = 0.f, t3 = 0.f;
                if (m < M) {
                    int k;
                    k = kk + 0; if (k < K) t0 = (k < K1) ? A1[(long)m * lda1 + k] : A2[(long)m * lda2 + (k - K1)];
                    k = kk + 1; if (k < K) t1 = (k < K1) ? A1[(long)m * lda1 + k] : A2[(long)m * lda2 + (k - K1)];
                    k = kk + 2; if (k < K) t2 = (k < K1) ? A1[(long)m * lda1 + k] : A2[(long)m * lda2 + (k - K1)];
                    k = kk + 3; if (k < K) t3 = (k < K1) ? A1[(long)m * lda1 + k] : A2[(long)m * lda2 + (k - K1)];
                }
                v = make_float4(t0, t1, t2, t3);
            }
            As[kq + 0][row] = v.x; As[kq + 1][row] = v.y;
            As[kq + 2][row] = v.z; As[kq + 3][row] = v.w;
        }
        #pragma unroll
        for (int c = tid; c < 512; c += 256) {
            int row = c >> 5, nq = (c & 31) << 2;
            int k = k0 + row, n = n0 + nq;
            float4 v = make_float4(0.f, 0.f, 0.f, 0.f);
            if (k < K) {
                if (n + 3 < N) {
                    v = *(const float4*)&Bm[(long)k * ldb + n];
                } else {
                    float t[4] = {0.f, 0.f, 0.f, 0.f};
                    #pragma unroll
                    for (int j = 0; j < 4; ++j) if (n + j < N) t[j] = Bm[(long)k * ldb + n + j];
                    v = make_float4(t[0], t[1], t[2], t[3]);
                }
            }
            *(float4*)&Bs[row][nq] = v;
        }
        __syncthreads();
        #pragma unroll
        for (int k = 0; k < 16; ++k) {
            float4 a0 = *(const float4*)&As[k][(ty << 3)];
            float4 a1 = *(const float4*)&As[k][(ty << 3) + 4];
            float4 b0 = *(const float4*)&Bs[k][(tx << 3)];
            float4 b1 = *(const float4*)&Bs[k][(tx << 3) + 4];
            float av[8] = {a0.x, a0.y, a0.z, a0.w, a1.x, a1.y, a1.z, a1.w};
            float bv[8] = {b0.x, b0.y, b0.z, b0.w, b1.x, b1.y, b1.z, b1.w};
            #pragma unroll
            for (int i = 0; i < 8; ++i)
                #pragma unroll
                for (int j = 0; j < 8; ++j)
                    acc[i][j] = fmaf(av[i], bv[j], acc[i][j]);
        }
        __syncthreads();
    }
    #pragma unroll
    for (int i = 0; i < 8; ++i) {
        int m = m0 + (ty << 3) + i;
        if (m >= M) break;
        #pragma unroll
        for (int j = 0; j < 8; ++j) {
            int n = n0 + (tx << 3) + j;
            if (n >= N) continue;
            float v = acc[i][j];
            if (mode >= 1) v += bias[n];
            if (mode == 2) v = (v > 20.f) ? v : log1pf(expf(v));
            C[(long)m * ldc + n] = v;
        }
    }
}

/* ---- depthwise causal conv (K=4) + SiLU: block=256 d, grid=(257,32,3) ---- */
__global__ __launch_bounds__(256) void k_conv(const float* __restrict__ cw,
                                              const float* __restrict__ cb, float* ws) {
    int d = threadIdx.x;
    int t = blockIdx.x, b = blockIdx.y, v = blockIdx.z;
    long m0 = (long)v * M1 + (long)b * FF;
    const float* xz = ws + XZ_OFF;
    float acc = cb[d];
    #pragma unroll
    for (int k = 0; k < 4; ++k) {
        int tt = t - 3 + k;
        if (tt >= 0) acc = fmaf(cw[d * 4 + k], xz[(m0 + tt) * (2 * DI) + d], acc);
    }
    float sg = 1.f / (1.f + exp2f(-LOG2E * acc));
    ws[XC_OFF + (m0 + t) * DI + d] = acc * sg;
}

/* ======== chunked selective scan: 3 passes over NC=8 time chunks ======== */

__global__ __launch_bounds__(256) void k_scan_part(float* ws) {
    int d = threadIdx.x;
    int c = blockIdx.x, b = blockIdx.y, v = blockIdx.z;
    long m0 = (long)v * M1 + (long)b * FF;
    int t0 = c * CS, t1 = (t0 + CS < FF) ? t0 + CS : FF;
    float A2[DSTATE], h[DSTATE];
    #pragma unroll
    for (int s = 0; s < DSTATE; ++s) { A2[s] = ws[ANEG_OFF + d * DSTATE + s]; h[s] = 0.f; }
    float sumdt = 0.f;
    const float* dtp = ws + DT_OFF;
    const float* xcp = ws + XC_OFF;
    const float* xd  = ws + EMB_OFF;
    for (int t = t0; t < t1; ++t) {
        long m = m0 + t;
        float dt = dtp[m * DI + d];
        float xc = xcp[m * DI + d];
        const float* bc = xd + m * 40;
        sumdt += dt;
        float dtxc = dt * xc;
        #pragma unroll
        for (int s = 0; s < DSTATE; ++s) {
            float dA = exp2f(dt * A2[s]);
            h[s] = fmaf(dA, h[s], dtxc * bc[8 + s]);
        }
    }
    long cb = ((long)v * BB + b) * NC + c;
    #pragma unroll
    for (int s = 0; s < DSTATE; ++s) ws[HEND_OFF + (cb * DSTATE + s) * 256 + d] = h[s];
    ws[SUMDT_OFF + cb * 256 + d] = sumdt;
}

__global__ __launch_bounds__(256) void k_scan_fix(float* ws) {
    int d = threadIdx.x;
    int b = blockIdx.x, v = blockIdx.y;
    float A2[DSTATE], prev[DSTATE];
    #pragma unroll
    for (int s = 0; s < DSTATE; ++s) { A2[s] = ws[ANEG_OFF + d * DSTATE + s]; prev[s] = 0.f; }
    long cb0 = ((long)v * BB + b) * NC;
    for (int c = 0; c < NC; ++c) {
        long cb = cb0 + c;
        float sd = ws[SUMDT_OFF + cb * 256 + d];
        #pragma unroll
        for (int s = 0; s < DSTATE; ++s) {
            long idx = HEND_OFF + (cb * DSTATE + s) * 256 + d;
            float he = ws[idx];
            ws[idx] = prev[s];
            prev[s] = fmaf(exp2f(A2[s] * sd), prev[s], he);
        }
    }
}

__global__ __launch_bounds__(256) void k_scan_out(const float* __restrict__ Dp, float* ws) {
    int d = threadIdx.x;
    int c = blockIdx.x, b = blockIdx.y, v = blockIdx.z;
    long m0 = (long)v * M1 + (long)b * FF;
    int t0 = c * CS, t1 = (t0 + CS < FF) ? t0 + CS : FF;
    long cb = ((long)v * BB + b) * NC + c;
    float A2[DSTATE], h[DSTATE];
    #pragma unroll
    for (int s = 0; s < DSTATE; ++s) {
        A2[s] = ws[ANEG_OFF + d * DSTATE + s];
        h[s]  = ws[HEND_OFF + (cb * DSTATE + s) * 256 + d];
    }
    float Dv = Dp[d];
    float* dtp = ws + DT_OFF;
    const float* xcp = ws + XC_OFF;
    const float* xzp = ws + XZ_OFF;
    const float* xd  = ws + EMB_OFF;
    for (int t = t0; t < t1; ++t) {
        long m = m0 + t;
        float dt = dtp[m * DI + d];
        float xc = xcp[m * DI + d];
        float z  = xzp[m * (2 * DI) + DI + d];
        const float* bc = xd + m * 40;
        float dtxc = dt * xc;
        float y = 0.f;
        #pragma unroll
        for (int s = 0; s < DSTATE; ++s) {
            float dA = exp2f(dt * A2[s]);
            h[s] = fmaf(dA, h[s], dtxc * bc[8 + s]);
            y = fmaf(h[s], bc[24 + s], y);
        }
        float yy = fmaf(xc, Dv, y);
        float sg = 1.f / (1.f + exp2f(-LOG2E * z));
        dtp[m * DI + d] = yy * (z * sg);
    }
}

/* ---- per-row L2 norm of enc[v] reshaped (32, 32896): grid=(32,3) ---- */
__global__ __launch_bounds__(256) void k_norm(float* ws) {
    int i = blockIdx.x, v = blockIdx.y;
    const float* row = ws + ENC_OFF + (long)v * M1 * DM + (long)i * FF * DM;
    float acc = 0.f;
    for (int q = threadIdx.x; q < FF * DM; q += 256) { float xv = row[q]; acc = fmaf(xv, xv, acc); }
    __shared__ float red[256];
    red[threadIdx.x] = acc; __syncthreads();
    for (int s = 128; s > 0; s >>= 1) { if (threadIdx.x < s) red[threadIdx.x] += red[threadIdx.x + s]; __syncthreads(); }
    if (threadIdx.x == 0) ws[NRM_OFF + v * 32 + i] = sqrtf(red[0]);
}

/* ---- Gram dots enc0 · enc{1,2}: grid=(32 j, 32 i, 2 p) ---- */
__global__ __launch_bounds__(256) void k_sim(float* ws) {
    int j = blockIdx.x, i = blockIdx.y, p = blockIdx.z;
    const float* r1 = ws + ENC_OFF + (long)i * FF * DM;
    const float* r2 = ws + ENC_OFF + (long)(p + 1) * M1 * DM + (long)j * FF * DM;
    float acc = 0.f;
    for (int q = threadIdx.x; q < FF * DM; q += 256) acc = fmaf(r1[q], r2[q], acc);
    __shared__ float red[256];
    red[threadIdx.x] = acc; __syncthreads();
    for (int s = 128; s > 0; s >>= 1) { if (threadIdx.x < s) red[threadIdx.x] += red[threadIdx.x + s]; __syncthreads(); }
    if (threadIdx.x == 0) ws[SIM_OFF + p * 1024 + i * 32 + j] = red[0];
}

/* ---- NT-Xent losses, 1 block of 64 threads (p = tid>>5, i = tid&31) ---- */
__global__ void k_loss(float* ws, float* out) {
    int tid = threadIdx.x;
    int p = tid >> 5, i = tid & 31;
    float ni = ws[NRM_OFF + i];
    float sum = 0.f, pos = 0.f;
    for (int j = 0; j < 32; ++j) {
        float nj = ws[NRM_OFF + (p + 1) * 32 + j];
        float sim = ws[SIM_OFF + p * 1024 + i * 32 + j] / (ni * nj);
        float e = expf(sim * 2.0f);   /* /TEMP, TEMP=0.5 */
        sum += e;
        if (j == i) pos = e;
    }
    float l = -logf(pos / (sum - pos));
    for (int off = 32; off > 0; off >>= 1) l += __shfl_down(l, off, 64);
    if (tid == 0) out[(long)BB * WINL * CHN] = l / 32.f;
}

/* ---- recon loss: two-stage deterministic reduction ---- */
__global__ __launch_bounds__(256) void k_recon_part(float* ws) {
    float acc = 0.f;
    const float* sre = ws + SFRE_OFF;
    const float* sim = ws + SFIM_OFF;
    const float* re  = ws + REAL_OFF;
    const float* im  = ws + IMAG_OFF;
    for (long q = (long)blockIdx.x * 256 + threadIdx.x; q < (long)M1 * CHN; q += 512L * 256) {
        float dr = sre[q] - re[q];
        float di = sim[q] - im[q];
        acc = fmaf(dr, dr, acc);
        acc = fmaf(di, di, acc);
    }
    __shared__ float red[256];
    red[threadIdx.x] = acc; __syncthreads();
    for (int s = 128; s > 0; s >>= 1) { if (threadIdx.x < s) red[threadIdx.x] += red[threadIdx.x + s]; __syncthreads(); }
    if (threadIdx.x == 0) ws[RED_OFF + blockIdx.x] = red[0];
}
__global__ __launch_bounds__(512) void k_recon_final(float* ws, float* out) {
    __shared__ float red[512];
    red[threadIdx.x] = ws[RED_OFF + threadIdx.x];
    __syncthreads();
    for (int s = 256; s > 0; s >>= 1) { if (threadIdx.x < s) red[threadIdx.x] += red[threadIdx.x + s]; __syncthreads(); }
    if (threadIdx.x == 0) out[(long)BB * WINL * CHN + 1] = red[0] / (float)((long)M1 * CHN);
}

/* ---- irfft via radix-8 decimation in frequency-index (Hermitian full sum) ----
   thread (ch, tau): H_r[tau] = sum_u Z_{8u+r} w_512^{+8u*tau};
   out_{tau+64m} = (1/512) Re( sum_r w_512^{+r*t} H_r ).  grid=(16,BB), block=(64,4). */
__global__ __launch_bounds__(256) void k_irfft(float* ws, float* __restrict__ out) {
    __shared__ float twc[512], tws[512];
    int tid = threadIdx.y * 64 + threadIdx.x;
    for (int q = tid; q < 512; q += 256) { twc[q] = ws[TW_OFF + q]; tws[q] = ws[TW_OFF + 512 + q]; }
    __syncthreads();
    int ch  = threadIdx.x;
    int tau = blockIdx.x * 4 + threadIdx.y;   /* 0..63 */
    int b   = blockIdx.y;
    const float* re = ws + REAL_OFF + (long)b * FF * CHN + ch;
    const float* im = ws + IMAG_OFF + (long)b * FF * CHN + ch;
    float hr[8], hi[8];
    #pragma unroll
    for (int r = 0; r < 8; ++r) { hr[r] = 0.f; hi[r] = 0.f; }
    int idx = 0, step = (8 * tau) & 511;
    /* u = 0..31: f = 8u+r in [0,255], direct */
    for (int u = 0; u < 32; ++u) {
        float c = twc[idx], s = tws[idx];
        #pragma unroll
        for (int r = 0; r < 8; ++r) {
            float zr = re[(long)(8 * u + r) * CHN];
            float zi = im[(long)(8 * u + r) * CHN];
            hr[r] += zr * c - zi * s;
            hi[r] += zr * s + zi * c;
        }
        idx = (idx + step) & 511;
    }
    /* c2r: DC imag is ignored; at u=0 (c=1,s=0) it polluted hi[0] only */
    hi[0] -= im[0];
    /* u = 32: f=256 (nyquist, imag ignored) + f=257..263 -> mirror 255..249 */
    {
        float c = twc[idx], s = tws[idx];
        float zr = re[(long)256 * CHN];
        hr[0] += zr * c;
        hi[0] += zr * s;
        #pragma unroll
        for (int r = 1; r < 8; ++r) {
            float zr2 =  re[(long)(256 - r) * CHN];
            float zi2 = -im[(long)(256 - r) * CHN];
            hr[r] += zr2 * c - zi2 * s;
            hi[r] += zr2 * s + zi2 * c;
        }
        idx = (idx + step) & 511;
    }
    /* u = 33..63: f = 8u+r in [264,511] -> conj at f' = 512-8u-r in [1,248] */
    for (int u = 33; u < 64; ++u) {
        float c = twc[idx], s = tws[idx];
        int base = 512 - 8 * u;
        #pragma unroll
        for (int r = 0; r < 8; ++r) {
            float zr =  re[(long)(base - r) * CHN];
            float zi = -im[(long)(base - r) * CHN];
            hr[r] += zr * c - zi * s;
            hi[r] += zr * s + zi * c;
        }
        idx = (idx + step) & 511;
    }
    /* combine: t = tau + 64m */
    #pragma unroll
    for (int m = 0; m < 8; ++m) {
        int t = tau + 64 * m;
        float acc = 0.f;
        int i2 = 0;
        #pragma unroll
        for (int r = 0; r < 8; ++r) {
            float c2 = twc[i2], s2 = tws[i2];
            acc += hr[r] * c2 - hi[r] * s2;
            i2 = (i2 + t) & 511;
        }
        out[((long)b * WINL + t) * CHN + ch] = acc * (1.f / 512.f);
    }
}

extern "C" void kernel_launch(void* const* d_in, const int* in_sizes, int n_in,
                              void* d_out, int out_size, void* d_ws, size_t ws_size,
                              hipStream_t stream) {
    const float* x          = (const float*)d_in[0];
    const float* jitter     = (const float*)d_in[1];
    const float* u_mask     = (const float*)d_in[2];
    const float* fre_w      = (const float*)d_in[3];
    const float* fre_b      = (const float*)d_in[4];
    const float* in_proj_w  = (const float*)d_in[5];
    const float* conv_w     = (const float*)d_in[6];
    const float* conv_b     = (const float*)d_in[7];
    const float* xproj_w    = (const float*)d_in[8];
    const float* dtproj_w   = (const float*)d_in[9];
    const float* dtproj_b   = (const float*)d_in[10];
    const float* A_log      = (const float*)d_in[11];
    const float* D_param    = (const float*)d_in[12];
    const float* out_proj_w = (const float*)d_in[13];
    const float* getr_w     = (const float*)d_in[14];
    const float* getr_b     = (const float*)d_in[15];
    const float* geti_w     = (const float*)d_in[16];
    const float* geti_b     = (const float*)d_in[17];
    float* ws  = (float*)d_ws;
    float* out = (float*)d_out;

    const int GY3 = (M3 + 127) / 128;   /* 193 */
    const int GY1 = (M1 + 127) / 128;   /* 65  */

    k_init<<<18, 256, 0, stream>>>(ws, A_log);
    k_aug<<<4096, 256, 0, stream>>>(x, jitter, u_mask, ws);
    k_dft<<<dim3(16, 32, 3), dim3(64, 4), 0, stream>>>(x, ws);

    /* embed: [Re||Im] @ fre_w + fre_b -> EMB */
    k_gemm_t<<<dim3(1, GY3), 256, 0, stream>>>(
        ws + SFRE_OFF, CHN, CHN, ws + SFIM_OFF, CHN,
        fre_w, DM, fre_b, ws + EMB_OFF, DM, M3, DM, 2 * CHN, 1);

    /* in_proj: EMB @ in_proj_w -> XZ */
    k_gemm_t<<<dim3(4, GY3), 256, 0, stream>>>(
        ws + EMB_OFF, DM, DM, nullptr, 0,
        in_proj_w, 2 * DI, nullptr, ws + XZ_OFF, 2 * DI, M3, 2 * DI, DM, 0);

    k_conv<<<dim3(FF, BB, 3), 256, 0, stream>>>(conv_w, conv_b, ws);

    /* xproj: XC @ xproj_w -> XDBL (in EMB region) */
    k_gemm_t<<<dim3(1, GY3), 256, 0, stream>>>(
        ws + XC_OFF, DI, DI, nullptr, 0,
        xproj_w, 40, nullptr, ws + EMB_OFF, 40, M3, 40, DI, 0);

    /* dtproj + softplus: XDBL[:, :8] @ dtproj_w + b -> DT */
    k_gemm_t<<<dim3(2, GY3), 256, 0, stream>>>(
        ws + EMB_OFF, 40, 8, nullptr, 0,
        dtproj_w, DI, dtproj_b, ws + DT_OFF, DI, M3, DI, 8, 2);

    /* chunked selective scan */
    k_scan_part<<<dim3(NC, BB, 3), 256, 0, stream>>>(ws);
    k_scan_fix<<<dim3(BB, 3), 256, 0, stream>>>(ws);
    k_scan_out<<<dim3(NC, BB, 3), 256, 0, stream>>>(D_param, ws);

    /* out_proj: Y @ out_proj_w -> ENC */
    k_gemm_t<<<dim3(1, GY3), 256, 0, stream>>>(
        ws + DT_OFF, DI, DI, nullptr, 0,
        out_proj_w, DM, nullptr, ws + ENC_OFF, DM, M3, DM, DI, 0);

    /* heads: enc0 @ getr_w/geti_w + b -> REAL/IMAG */
    k_gemm_t<<<dim3(1, GY1), 256, 0, stream>>>(
        ws + ENC_OFF, DM, DM, nullptr, 0,
        getr_w, CHN, getr_b, ws + REAL_OFF, CHN, M1, CHN, DM, 1);
    k_gemm_t<<<dim3(1, GY1), 256, 0, stream>>>(
        ws + ENC_OFF, DM, DM, nullptr, 0,
        geti_w, CHN, geti_b, ws + IMAG_OFF, CHN, M1, CHN, DM, 1);

    k_norm<<<dim3(32, 3), 256, 0, stream>>>(ws);
    k_sim<<<dim3(32, 32, 2), 256, 0, stream>>>(ws);
    k_loss<<<1, 64, 0, stream>>>(ws, out);
    k_recon_part<<<512, 256, 0, stream>>>(ws);
    k_recon_final<<<1, 512, 0, stream>>>(ws, out);
    k_irfft<<<dim3(16, 32), dim3(64, 4), 0, stream>>>(ws, out);
}